// Round 1
// baseline (16423.254 us; speedup 1.0000x reference)
//
#include <hip/hip_runtime.h>

// Problem constants
#define B_   128
#define L_   4096
#define H_   1024
#define Z_   256
#define T_   16
#define G4H  4096   // 4*H

// ---------------- GEMM: C[M,N] = (Cin? Cin:0) + alpha * A[M,K] @ W[N,K]^T + (bias? bias[n]:0)
// A row-major (lda), W row-major N x K (ldw), C row-major (ldc = N).
#define BM 64
#define BN 64
#define BK 16

__global__ __launch_bounds__(256) void gemm_fp32(
    const float* __restrict__ A, int lda,
    const float* __restrict__ W, int ldw,
    const float* __restrict__ Cin,
    const float* __restrict__ bias,
    float* __restrict__ C,
    int M, int N, int K, float alpha)
{
    __shared__ float As[BK][BM + 1];
    __shared__ float Ws[BK][BN + 1];
    const int bn = blockIdx.x * BN;
    const int bm = blockIdx.y * BM;
    const int tid = threadIdx.x;
    const int tr = tid & 15;   // n-sub (x4)
    const int tc = tid >> 4;   // m-sub (x4)

    float acc[4][4] = {};

    for (int k0 = 0; k0 < K; k0 += BK) {
#pragma unroll
        for (int i = 0; i < 4; ++i) {
            int idx = tid + i * 256;           // 0..1023
            int r = idx >> 4, kk = idx & 15;   // r: 0..63 row, kk: 0..15
            As[kk][r] = A[(size_t)(bm + r) * lda + k0 + kk];
        }
#pragma unroll
        for (int i = 0; i < 4; ++i) {
            int idx = tid + i * 256;
            int r = idx >> 4, kk = idx & 15;
            Ws[kk][r] = W[(size_t)(bn + r) * ldw + k0 + kk];
        }
        __syncthreads();
#pragma unroll
        for (int kk = 0; kk < BK; ++kk) {
            float a[4], b[4];
#pragma unroll
            for (int i = 0; i < 4; ++i) a[i] = As[kk][tc * 4 + i];
#pragma unroll
            for (int j = 0; j < 4; ++j) b[j] = Ws[kk][tr * 4 + j];
#pragma unroll
            for (int i = 0; i < 4; ++i)
#pragma unroll
                for (int j = 0; j < 4; ++j)
                    acc[i][j] += a[i] * b[j];
        }
        __syncthreads();
    }

#pragma unroll
    for (int i = 0; i < 4; ++i) {
        int m = bm + tc * 4 + i;
#pragma unroll
        for (int j = 0; j < 4; ++j) {
            int n = bn + tr * 4 + j;
            float v = alpha * acc[i][j];
            if (Cin)  v += Cin[(size_t)m * N + n];
            if (bias) v += bias[n];
            C[(size_t)m * N + n] = v;
        }
    }
}

// ---------------- pointwise kernels ----------------
__device__ __forceinline__ float sigf(float x) { return 1.0f / (1.0f + expf(-x)); }

__global__ void sigmoid_k(const float* __restrict__ in, float* __restrict__ out, int n) {
    int i = blockIdx.x * blockDim.x + threadIdx.x;
    if (i < n) out[i] = sigf(in[i]);
}

// gates layout per batch row: [i(H) | f(H) | g(H) | o(H)]
__global__ void lstm_cell_k(const float* __restrict__ gates,
                            float* __restrict__ h, float* __restrict__ c,
                            int BH, int H) {
    int i = blockIdx.x * blockDim.x + threadIdx.x;
    if (i >= BH) return;
    int b = i / H, j = i - b * H;
    const float* g = gates + (size_t)b * 4 * H;
    float gi = g[j], gf = g[H + j], gg = g[2 * H + j], go = g[3 * H + j];
    float cn = sigf(gf) * c[i] + sigf(gi) * tanhf(gg);
    c[i] = cn;
    h[i] = sigf(go) * tanhf(cn);
}

__global__ void z_k(const float* __restrict__ eps_t, const float* __restrict__ mu,
                    const float* __restrict__ ls, float* __restrict__ z, int n) {
    int i = blockIdx.x * blockDim.x + threadIdx.x;
    if (i < n) z[i] = eps_t[i] * expf(ls[i]) + mu[i];
}

__global__ void init_k(const float* __restrict__ c0,
                       const float* __restrict__ h0e, const float* __restrict__ h0d,
                       float* __restrict__ c_t,
                       float* __restrict__ h_enc, float* __restrict__ c_enc,
                       float* __restrict__ h_dec, float* __restrict__ c_dec,
                       int BL, int BH, int L, int H) {
    int i = blockIdx.x * blockDim.x + threadIdx.x;
    if (i < BL) c_t[i] = c0[i % L];
    if (i < BH) {
        int j = i % H;
        h_enc[i] = h0e[j];
        c_enc[i] = 0.0f;
        h_dec[i] = h0d[j];
        c_dec[i] = 0.0f;
    }
}

__global__ void biasprep_k(const float* __restrict__ bie, const float* __restrict__ bhe,
                           const float* __restrict__ bid, const float* __restrict__ bhd,
                           float* __restrict__ be, float* __restrict__ bd, int n) {
    int i = blockIdx.x * blockDim.x + threadIdx.x;
    if (i < n) { be[i] = bie[i] + bhe[i]; bd[i] = bid[i] + bhd[i]; }
}

// ---------------- launch ----------------
extern "C" void kernel_launch(void* const* d_in, const int* in_sizes, int n_in,
                              void* d_out, int out_size, void* d_ws, size_t ws_size,
                              hipStream_t stream) {
    const float* x       = (const float*)d_in[0];   // B x L
    const float* eps     = (const float*)d_in[1];   // T x B x Z
    const float* c0      = (const float*)d_in[2];   // 1 x L
    const float* h0e     = (const float*)d_in[3];   // H
    const float* h0d     = (const float*)d_in[4];   // H
    const float* W_ih_e  = (const float*)d_in[5];   // 4H x (2L+H) = 4096 x 9216
    const float* b_ih_e  = (const float*)d_in[6];
    const float* W_hh_e  = (const float*)d_in[7];   // 4H x H
    const float* b_hh_e  = (const float*)d_in[8];
    const float* W_mu    = (const float*)d_in[9];   // Z x H
    const float* b_mu    = (const float*)d_in[10];
    const float* W_sig   = (const float*)d_in[11];  // Z x H
    const float* b_sig   = (const float*)d_in[12];
    const float* W_ih_d  = (const float*)d_in[13];  // 4H x Z
    const float* b_ih_d  = (const float*)d_in[14];
    const float* W_hh_d  = (const float*)d_in[15];  // 4H x H
    const float* b_hh_d  = (const float*)d_in[16];
    const float* W_wr    = (const float*)d_in[17];  // L x H
    const float* b_wr    = (const float*)d_in[18];

    float* out = (float*)d_out;                     // B x L fp32

    const int ldWihE = 2 * L_ + H_;  // 9216

    // workspace carve
    float* ws = (float*)d_ws;
    float* c_t     = ws;               ws += (size_t)B_ * L_;
    float* s_buf   = ws;               ws += (size_t)B_ * L_;
    float* base    = ws;               ws += (size_t)B_ * G4H;
    float* gates_e = ws;               ws += (size_t)B_ * G4H;
    float* gates_d = ws;               ws += (size_t)B_ * G4H;
    float* h_enc   = ws;               ws += (size_t)B_ * H_;
    float* c_enc   = ws;               ws += (size_t)B_ * H_;
    float* h_dec   = ws;               ws += (size_t)B_ * H_;
    float* c_dec   = ws;               ws += (size_t)B_ * H_;
    float* mu      = ws;               ws += (size_t)B_ * Z_;
    float* lsg     = ws;               ws += (size_t)B_ * Z_;
    float* z       = ws;               ws += (size_t)B_ * Z_;
    float* be      = ws;               ws += G4H;
    float* bd      = ws;               ws += G4H;

    const int BL = B_ * L_;   // 524288
    const int BH = B_ * H_;   // 131072
    const int BZ = B_ * Z_;   // 32768

    dim3 blk(256);
    dim3 gridBL((BL + 255) / 256);
    dim3 gridBH((BH + 255) / 256);
    dim3 gridBZ((BZ + 255) / 256);

    // init states + combined biases
    hipLaunchKernelGGL(init_k, gridBL, blk, 0, stream,
                       c0, h0e, h0d, c_t, h_enc, c_enc, h_dec, c_dec, BL, BH, L_, H_);
    hipLaunchKernelGGL(biasprep_k, dim3((G4H + 255) / 256), blk, 0, stream,
                       b_ih_e, b_hh_e, b_ih_d, b_hh_d, be, bd, G4H);

    dim3 gGemmBig(G4H / BN, B_ / BM);   // 64 x 2
    dim3 gGemmZ(Z_ / BN, B_ / BM);      // 4 x 2

    // base = be + x @ (Wx)^T + x @ (Wxhat)^T  (time-invariant part of encoder gates)
    hipLaunchKernelGGL(gemm_fp32, gGemmBig, blk, 0, stream,
                       x, L_, W_ih_e, ldWihE, (const float*)nullptr, be, base,
                       B_, G4H, L_, 1.0f);
    hipLaunchKernelGGL(gemm_fp32, gGemmBig, blk, 0, stream,
                       x, L_, W_ih_e + L_, ldWihE, base, (const float*)nullptr, base,
                       B_, G4H, L_, 1.0f);

    for (int t = 0; t < T_; ++t) {
        // s = sigmoid(c_t)
        hipLaunchKernelGGL(sigmoid_k, gridBL, blk, 0, stream, c_t, s_buf, BL);
        // gates_e = base - s @ Wxhat^T
        hipLaunchKernelGGL(gemm_fp32, gGemmBig, blk, 0, stream,
                           s_buf, L_, W_ih_e + L_, ldWihE, base, (const float*)nullptr,
                           gates_e, B_, G4H, L_, -1.0f);
        // gates_e += h_dec @ Whdec^T
        hipLaunchKernelGGL(gemm_fp32, gGemmBig, blk, 0, stream,
                           h_dec, H_, W_ih_e + 2 * L_, ldWihE, gates_e, (const float*)nullptr,
                           gates_e, B_, G4H, H_, 1.0f);
        // gates_e += h_enc @ W_hh_e^T
        hipLaunchKernelGGL(gemm_fp32, gGemmBig, blk, 0, stream,
                           h_enc, H_, W_hh_e, H_, gates_e, (const float*)nullptr,
                           gates_e, B_, G4H, H_, 1.0f);
        // encoder LSTM cell
        hipLaunchKernelGGL(lstm_cell_k, gridBH, blk, 0, stream, gates_e, h_enc, c_enc, BH, H_);
        // mu / logsigma
        hipLaunchKernelGGL(gemm_fp32, gGemmZ, blk, 0, stream,
                           h_enc, H_, W_mu, H_, (const float*)nullptr, b_mu,
                           mu, B_, Z_, H_, 1.0f);
        hipLaunchKernelGGL(gemm_fp32, gGemmZ, blk, 0, stream,
                           h_enc, H_, W_sig, H_, (const float*)nullptr, b_sig,
                           lsg, B_, Z_, H_, 1.0f);
        // z = eps_t * exp(logsigma) + mu
        hipLaunchKernelGGL(z_k, gridBZ, blk, 0, stream,
                           eps + (size_t)t * BZ, mu, lsg, z, BZ);
        // gates_d = bd + z @ W_ih_d^T
        hipLaunchKernelGGL(gemm_fp32, gGemmBig, blk, 0, stream,
                           z, Z_, W_ih_d, Z_, (const float*)nullptr, bd,
                           gates_d, B_, G4H, Z_, 1.0f);
        // gates_d += h_dec @ W_hh_d^T
        hipLaunchKernelGGL(gemm_fp32, gGemmBig, blk, 0, stream,
                           h_dec, H_, W_hh_d, H_, gates_d, (const float*)nullptr,
                           gates_d, B_, G4H, H_, 1.0f);
        // decoder LSTM cell
        hipLaunchKernelGGL(lstm_cell_k, gridBH, blk, 0, stream, gates_d, h_dec, c_dec, BH, H_);
        // c_t += h_dec @ W_wr^T + b_wr
        hipLaunchKernelGGL(gemm_fp32, gGemmBig, blk, 0, stream,
                           h_dec, H_, W_wr, H_, c_t, b_wr,
                           c_t, B_, L_, H_, 1.0f);
    }

    // out = sigmoid(c_t)
    hipLaunchKernelGGL(sigmoid_k, gridBL, blk, 0, stream, c_t, out, BL);
}

// Round 2
// 921.773 us; speedup vs baseline: 17.8170x; 17.8170x over previous
//
#include <hip/hip_runtime.h>

#define B_   128
#define L_   4096
#define H_   1024
#define Z_   256
#define T_   16
#define G4H  4096
#define SPLITS 4

typedef __bf16 bf16;
typedef __bf16 bf16x8 __attribute__((ext_vector_type(8)));
typedef float f32x4 __attribute__((ext_vector_type(4)));

// ---------------------------------------------------------------------------
// bf16 MFMA GEMM: out_slice[z] = A[128 x K] @ W[N x K]^T  (chunk z of K)
// A row-major lda, W row-major ldw, out: SPLITS slices of 128 x N fp32.
// Block tile 64x64, BK=64, 4 waves (each 32x32), double-buffered LDS,
// global_load_lds(16B) with XOR-swizzled source + swizzled ds_read_b128.
// ---------------------------------------------------------------------------
__global__ __launch_bounds__(256) void gemm_bf16(
    const bf16* __restrict__ A, int lda,
    const bf16* __restrict__ W, int ldw,
    float* __restrict__ out, int N, int Kc)
{
    __shared__ bf16 As[2][64 * 64];
    __shared__ bf16 Bs[2][64 * 64];
    const int bn = blockIdx.x * 64;
    const int bm = blockIdx.y * 64;
    const int ks = blockIdx.z * Kc;
    const int tid  = threadIdx.x;
    const int lane = tid & 63;
    const int wave = tid >> 6;
    const int wr = wave & 1, wc = wave >> 1;

    const int srow = lane >> 3;                        // row-within-chunk 0..7
    const int scol = ((lane & 7) ^ srow) << 3;         // swizzled source col (elems)

    f32x4 acc00 = {0.f, 0.f, 0.f, 0.f};
    f32x4 acc01 = {0.f, 0.f, 0.f, 0.f};
    f32x4 acc10 = {0.f, 0.f, 0.f, 0.f};
    f32x4 acc11 = {0.f, 0.f, 0.f, 0.f};

#define GLL(SRC, DST) __builtin_amdgcn_global_load_lds( \
    (const __attribute__((address_space(1))) void*)(SRC), \
    (__attribute__((address_space(3))) void*)(DST), 16, 0, 0)

#define STAGE(BUF, KOFF) do { \
    int c0_ = wave, c1_ = wave + 4; \
    int ra0_ = c0_ * 8 + srow, ra1_ = c1_ * 8 + srow; \
    GLL(A + (size_t)(bm + ra0_) * lda + ks + (KOFF) + scol, &As[(BUF)][c0_ * 512]); \
    GLL(A + (size_t)(bm + ra1_) * lda + ks + (KOFF) + scol, &As[(BUF)][c1_ * 512]); \
    GLL(W + (size_t)(bn + ra0_) * ldw + ks + (KOFF) + scol, &Bs[(BUF)][c0_ * 512]); \
    GLL(W + (size_t)(bn + ra1_) * ldw + ks + (KOFF) + scol, &Bs[(BUF)][c1_ * 512]); \
} while (0)

    const int nk = Kc >> 6;
    STAGE(0, 0);
    int buf = 0;

    const int q   = lane >> 4;
    const int rA0 = wr * 32 + (lane & 15);
    const int rA1 = rA0 + 16;
    const int rB0 = wc * 32 + (lane & 15);
    const int rB1 = rB0 + 16;
    const int sw  = (lane & 7) << 4;                   // swizzle byte XOR

    for (int t = 0; t < nk; ++t) {
        __syncthreads();
        if (t + 1 < nk) STAGE(buf ^ 1, (t + 1) << 6);
        const bf16* as = As[buf];
        const bf16* bs = Bs[buf];
#pragma unroll
        for (int k2 = 0; k2 < 2; ++k2) {
            int ko = ((((k2 << 6) | (q << 4)) ^ sw) >> 1);  // elem offset in row
            bf16x8 a0 = *(const bf16x8*)&as[rA0 * 64 + ko];
            bf16x8 a1 = *(const bf16x8*)&as[rA1 * 64 + ko];
            bf16x8 b0 = *(const bf16x8*)&bs[rB0 * 64 + ko];
            bf16x8 b1 = *(const bf16x8*)&bs[rB1 * 64 + ko];
            acc00 = __builtin_amdgcn_mfma_f32_16x16x32_bf16(a0, b0, acc00, 0, 0, 0);
            acc01 = __builtin_amdgcn_mfma_f32_16x16x32_bf16(a0, b1, acc01, 0, 0, 0);
            acc10 = __builtin_amdgcn_mfma_f32_16x16x32_bf16(a1, b0, acc10, 0, 0, 0);
            acc11 = __builtin_amdgcn_mfma_f32_16x16x32_bf16(a1, b1, acc11, 0, 0, 0);
        }
        buf ^= 1;
    }

    float* os = out + (size_t)blockIdx.z * (size_t)(128) * N;
    const int row0 = bm + wr * 32 + q * 4;
    const int col0 = bn + wc * 32 + (lane & 15);
#pragma unroll
    for (int r2 = 0; r2 < 4; ++r2) {
        os[(size_t)(row0 + r2) * N + col0]           = acc00[r2];
        os[(size_t)(row0 + r2) * N + col0 + 16]      = acc01[r2];
        os[(size_t)(row0 + 16 + r2) * N + col0]      = acc10[r2];
        os[(size_t)(row0 + 16 + r2) * N + col0 + 16] = acc11[r2];
    }
#undef STAGE
#undef GLL
}

// ---------------- pointwise ----------------
__device__ __forceinline__ float sigf(float x) { return 1.0f / (1.0f + expf(-x)); }

#define PBL (B_ * L_)      // 524288
#define PBH (B_ * H_)      // 131072
#define PBZ (B_ * Z_)      // 32768

__global__ void init_k(const float* __restrict__ x, const float* __restrict__ c0,
                       const float* __restrict__ h0e, const float* __restrict__ h0d,
                       float* __restrict__ c_t, float* __restrict__ c_enc,
                       float* __restrict__ c_dec, bf16* __restrict__ act_enc,
                       bf16* __restrict__ act_dec, bf16* __restrict__ x_bf) {
    int i = blockIdx.x * 256 + threadIdx.x;
    if (i >= PBL) return;
    int b = i >> 12, n = i & 4095;
    float c = c0[n];
    c_t[i] = c;
    act_enc[(size_t)b * 6144 + n] = (bf16)(-sigf(c));
    x_bf[i] = (bf16)x[i];
    if (i < PBH) {
        int b2 = i >> 10, j = i & 1023;
        c_enc[i] = 0.f;
        c_dec[i] = 0.f;
        bf16 hd = (bf16)h0d[j], he = (bf16)h0e[j];
        act_enc[(size_t)b2 * 6144 + 4096 + j] = hd;
        act_enc[(size_t)b2 * 6144 + 5120 + j] = he;
        act_dec[(size_t)b2 * 1280 + 256 + j]  = hd;
    }
}

__global__ void base_fin_k(const float* __restrict__ p, const float* __restrict__ bie,
                           const float* __restrict__ bhe, float* __restrict__ base) {
    int i = blockIdx.x * 256 + threadIdx.x;
    if (i >= PBL) return;
    int n = i & 4095;
    base[i] = bie[n] + bhe[n] + p[i] + p[i + PBL] + p[i + 2 * PBL] + p[i + 3 * PBL];
}

__global__ void lstm_enc_k(const float* __restrict__ ge, const float* __restrict__ base,
                           float* __restrict__ c_enc, bf16* __restrict__ act_enc) {
    int i = blockIdx.x * 256 + threadIdx.x;
    if (i >= PBH) return;
    int b = i >> 10, j = i & 1023;
    size_t r = (size_t)b * G4H;
    float g[4];
#pragma unroll
    for (int qg = 0; qg < 4; ++qg) {
        size_t idx = r + qg * 1024 + j;
        g[qg] = base[idx] + ge[idx] + ge[idx + PBL] + ge[idx + 2 * PBL] + ge[idx + 3 * PBL];
    }
    float cn = sigf(g[1]) * c_enc[i] + sigf(g[0]) * tanhf(g[2]);
    c_enc[i] = cn;
    float h = sigf(g[3]) * tanhf(cn);
    act_enc[(size_t)b * 6144 + 5120 + j] = (bf16)h;
}

__global__ void zmusig_k(const float* __restrict__ ms, const float* __restrict__ bmu,
                         const float* __restrict__ bsig, const float* __restrict__ eps_t,
                         bf16* __restrict__ act_dec) {
    int i = blockIdx.x * 256 + threadIdx.x;
    if (i >= PBZ) return;
    int b = i >> 8, zi = i & 255;
    size_t rb = (size_t)b * 512;
    float mu = bmu[zi], ls = bsig[zi];
#pragma unroll
    for (int s = 0; s < SPLITS; ++s) {
        mu += ms[(size_t)s * (B_ * 512) + rb + zi];
        ls += ms[(size_t)s * (B_ * 512) + rb + 256 + zi];
    }
    float z = eps_t[i] * expf(ls) + mu;
    act_dec[(size_t)b * 1280 + zi] = (bf16)z;
}

__global__ void lstm_dec_k(const float* __restrict__ gd, const float* __restrict__ bid,
                           const float* __restrict__ bhd, float* __restrict__ c_dec,
                           bf16* __restrict__ act_enc, bf16* __restrict__ act_dec) {
    int i = blockIdx.x * 256 + threadIdx.x;
    if (i >= PBH) return;
    int b = i >> 10, j = i & 1023;
    size_t r = (size_t)b * G4H;
    float g[4];
#pragma unroll
    for (int qg = 0; qg < 4; ++qg) {
        size_t idx = r + qg * 1024 + j;
        g[qg] = bid[qg * 1024 + j] + bhd[qg * 1024 + j]
              + gd[idx] + gd[idx + PBL] + gd[idx + 2 * PBL] + gd[idx + 3 * PBL];
    }
    float cn = sigf(g[1]) * c_dec[i] + sigf(g[0]) * tanhf(g[2]);
    c_dec[i] = cn;
    float h = sigf(g[3]) * tanhf(cn);
    bf16 hb = (bf16)h;
    act_enc[(size_t)b * 6144 + 4096 + j] = hb;
    act_dec[(size_t)b * 1280 + 256 + j]  = hb;
}

__global__ void ct_negs_k(const float* __restrict__ gw, const float* __restrict__ bwr,
                          float* __restrict__ c_t, bf16* __restrict__ act_enc) {
    int i = blockIdx.x * 256 + threadIdx.x;
    if (i >= PBL) return;
    int b = i >> 12, n = i & 4095;
    float c = c_t[i] + bwr[n] + gw[i] + gw[i + PBL] + gw[i + 2 * PBL] + gw[i + 3 * PBL];
    c_t[i] = c;
    act_enc[(size_t)b * 6144 + n] = (bf16)(-sigf(c));
}

__global__ void out_k(const float* __restrict__ c_t, float* __restrict__ out) {
    int i = blockIdx.x * 256 + threadIdx.x;
    if (i < PBL) out[i] = sigf(c_t[i]);
}

// ---------------- weight packing (fp32 -> bf16) ----------------
__global__ void conv_enc_k(const float* __restrict__ Wih, const float* __restrict__ Whh,
                           bf16* __restrict__ dst) {
    int id = blockIdx.x * 256 + threadIdx.x;
    if (id >= 4096 * 6144) return;
    int n = id / 6144, c = id - n * 6144;
    float v;
    if (c < 4096)       v = Wih[(size_t)n * 9216 + 4096 + c];
    else if (c < 5120)  v = Wih[(size_t)n * 9216 + 8192 + (c - 4096)];
    else                v = Whh[(size_t)n * 1024 + (c - 5120)];
    dst[id] = (bf16)v;
}

__global__ void conv_sum_k(const float* __restrict__ Wih, bf16* __restrict__ dst) {
    int id = blockIdx.x * 256 + threadIdx.x;
    if (id >= 4096 * 4096) return;
    int n = id >> 12, c = id & 4095;
    dst[id] = (bf16)(Wih[(size_t)n * 9216 + c] + Wih[(size_t)n * 9216 + 4096 + c]);
}

__global__ void conv_dec_k(const float* __restrict__ Wih, const float* __restrict__ Whh,
                           bf16* __restrict__ dst) {
    int id = blockIdx.x * 256 + threadIdx.x;
    if (id >= 4096 * 1280) return;
    int n = id / 1280, c = id - n * 1280;
    float v = (c < 256) ? Wih[(size_t)n * 256 + c] : Whh[(size_t)n * 1024 + (c - 256)];
    dst[id] = (bf16)v;
}

__global__ void conv_ms_k(const float* __restrict__ Wmu, const float* __restrict__ Wsig,
                          bf16* __restrict__ dst) {
    int id = blockIdx.x * 256 + threadIdx.x;
    if (id >= 512 * 1024) return;
    int n = id >> 10, c = id & 1023;
    float v = (n < 256) ? Wmu[(size_t)n * 1024 + c] : Wsig[(size_t)(n - 256) * 1024 + c];
    dst[id] = (bf16)v;
}

__global__ void conv_wr_k(const float* __restrict__ Wwr, bf16* __restrict__ dst) {
    int id = blockIdx.x * 256 + threadIdx.x;
    if (id >= 4096 * 1024) return;
    dst[id] = (bf16)Wwr[id];
}

// ---------------- launch ----------------
extern "C" void kernel_launch(void* const* d_in, const int* in_sizes, int n_in,
                              void* d_out, int out_size, void* d_ws, size_t ws_size,
                              hipStream_t stream) {
    const float* x      = (const float*)d_in[0];
    const float* eps    = (const float*)d_in[1];
    const float* c0     = (const float*)d_in[2];
    const float* h0e    = (const float*)d_in[3];
    const float* h0d    = (const float*)d_in[4];
    const float* W_ih_e = (const float*)d_in[5];
    const float* b_ih_e = (const float*)d_in[6];
    const float* W_hh_e = (const float*)d_in[7];
    const float* b_hh_e = (const float*)d_in[8];
    const float* W_mu   = (const float*)d_in[9];
    const float* b_mu   = (const float*)d_in[10];
    const float* W_sig  = (const float*)d_in[11];
    const float* b_sig  = (const float*)d_in[12];
    const float* W_ih_d = (const float*)d_in[13];
    const float* b_ih_d = (const float*)d_in[14];
    const float* W_hh_d = (const float*)d_in[15];
    const float* b_hh_d = (const float*)d_in[16];
    const float* W_wr   = (const float*)d_in[17];
    const float* b_wr   = (const float*)d_in[18];
    float* out = (float*)d_out;

    // workspace carve (fp32 region first, then bf16 region)
    size_t need = (size_t)(524288 * 2 + 3 * 4 * 524288 + 4 * 65536 + 2 * 131072) * 4
                + (size_t)(786432 + 163840 + 524288 + 25165824 + 16777216
                           + 5242880 + 524288 + 4194304) * 2;
    if (ws_size < need) return;

    float* f = (float*)d_ws;
    float* c_t   = f; f += 524288;
    float* base  = f; f += 524288;
    float* ge    = f; f += 4 * 524288;
    float* gd    = f; f += 4 * 524288;
    float* gw    = f; f += 4 * 524288;
    float* ms    = f; f += 4 * 65536;
    float* c_enc = f; f += 131072;
    float* c_dec = f; f += 131072;
    bf16* bp      = (bf16*)f;
    bf16* act_enc = bp; bp += (size_t)B_ * 6144;
    bf16* act_dec = bp; bp += (size_t)B_ * 1280;
    bf16* x_bf    = bp; bp += 524288;
    bf16* Wenc    = bp; bp += (size_t)4096 * 6144;
    bf16* Wsum    = bp; bp += (size_t)4096 * 4096;
    bf16* Wdec    = bp; bp += (size_t)4096 * 1280;
    bf16* Wms     = bp; bp += (size_t)512 * 1024;
    bf16* Wwr     = bp; bp += (size_t)4096 * 1024;

    dim3 blk(256);
    dim3 gBL((PBL + 255) / 256);
    dim3 gBH((PBH + 255) / 256);
    dim3 gBZ((PBZ + 255) / 256);
    dim3 gG(64, 2, SPLITS);     // N=4096 GEMMs
    dim3 gGms(8, 2, SPLITS);    // N=512 GEMM

    // prologue: init + weight packing
    init_k<<<gBL, blk, 0, stream>>>(x, c0, h0e, h0d, c_t, c_enc, c_dec, act_enc, act_dec, x_bf);
    conv_enc_k<<<(4096 * 6144 + 255) / 256, blk, 0, stream>>>(W_ih_e, W_hh_e, Wenc);
    conv_sum_k<<<(4096 * 4096 + 255) / 256, blk, 0, stream>>>(W_ih_e, Wsum);
    conv_dec_k<<<(4096 * 1280 + 255) / 256, blk, 0, stream>>>(W_ih_d, W_hh_d, Wdec);
    conv_ms_k<<<(512 * 1024 + 255) / 256, blk, 0, stream>>>(W_mu, W_sig, Wms);
    conv_wr_k<<<(4096 * 1024 + 255) / 256, blk, 0, stream>>>(W_wr, Wwr);

    // base = biases + x @ (Wx + Wxhat)^T   (partials into ge, then finalize)
    gemm_bf16<<<gG, blk, 0, stream>>>(x_bf, 4096, Wsum, 4096, ge, 4096, 1024);
    base_fin_k<<<gBL, blk, 0, stream>>>(ge, b_ih_e, b_hh_e, base);

    for (int t = 0; t < T_; ++t) {
        // encoder gates: [negs | h_dec | h_enc] @ Wenc^T   (K=6144)
        gemm_bf16<<<gG, blk, 0, stream>>>(act_enc, 6144, Wenc, 6144, ge, 4096, 1536);
        lstm_enc_k<<<gBH, blk, 0, stream>>>(ge, base, c_enc, act_enc);
        // mu / logsigma: h_enc @ [Wmu;Wsig]^T   (N=512, K=1024)
        gemm_bf16<<<gGms, blk, 0, stream>>>(act_enc + 5120, 6144, Wms, 1024, ms, 512, 256);
        zmusig_k<<<gBZ, blk, 0, stream>>>(ms, b_mu, b_sig, eps + (size_t)t * PBZ, act_dec);
        // decoder gates: [z | h_dec] @ Wdec^T   (K=1280)
        gemm_bf16<<<gG, blk, 0, stream>>>(act_dec, 1280, Wdec, 1280, gd, 4096, 320);
        lstm_dec_k<<<gBH, blk, 0, stream>>>(gd, b_ih_d, b_hh_d, c_dec, act_enc, act_dec);
        // write: c_t += h_dec @ Wwr^T + b_wr   (K=1024)
        gemm_bf16<<<gG, blk, 0, stream>>>(act_dec + 256, 1280, Wwr, 1024, gw, 4096, 256);
        ct_negs_k<<<gBL, blk, 0, stream>>>(gw, b_wr, c_t, act_enc);
    }

    out_k<<<gBL, blk, 0, stream>>>(c_t, out);
}